// Round 7
// baseline (2022.241 us; speedup 1.0000x reference)
//
#include <hip/hip_runtime.h>
#include <stdint.h>

typedef unsigned short u16;
typedef unsigned int u32;

#define DIM 128
#define DIM2 64  // h dwords per row (2 bf16 per dword)

__device__ __forceinline__ u32 f32_to_bf16_rne(float f) {
  u32 u = __float_as_uint(f);
  u32 r = u + 0x7fffu + ((u >> 16) & 1u);
  return r >> 16;
}
__device__ __forceinline__ float bf16_to_f32(u32 u) { return __uint_as_float(u << 16); }

// h = x @ W^T. fp32 inputs (contract-confirmed R6), fp32 VALU math (no fp32
// MFMA on CDNA4), bf16 h out (halves SpMM gather traffic; ~0.4% rel err).
// W^T staged in LDS at exactly 64 KB with additive swizzle (o+k)&127:
//  - stage: lane k varies -> bank (o+k)&31 hits each bank exactly 2x (free)
//  - read:  lanes o consecutive at fixed k -> consecutive dwords (free)
__global__ __launch_bounds__(256) void gemm_f32(const float* __restrict__ x,
                                                const float* __restrict__ W,
                                                u16* __restrict__ h, int N) {
  __shared__ float Wt[DIM * DIM];  // Wt[k*128 + ((o+k)&127)] = W[o*128+k]
  int tid = threadIdx.x;
  for (int idx = tid; idx < DIM * DIM; idx += 256) {
    int o = idx >> 7, k = idx & 127;
    Wt[k * DIM + ((o + k) & 127)] = W[idx];
  }
  __syncthreads();
  int r = tid >> 7, o = tid & 127;
  int node = blockIdx.x * 2 + r;
  if (node >= N) return;
  const float* xr = x + (size_t)node * DIM;
  float acc = 0.f;
#pragma unroll 8
  for (int k = 0; k < DIM; ++k)
    acc += xr[k] * Wt[k * DIM + ((o + k) & 127)];
  h[(size_t)node * DIM + o] = (u16)f32_to_bf16_rne(acc);
}

__global__ void zero_kernel(int* __restrict__ cnt, int* __restrict__ total, int N) {
  int i = blockIdx.x * blockDim.x + threadIdx.x;
  if (i < N) cnt[i] = 0;
  if (i == 0) *total = 0;
}

__global__ void hist_kernel(const int* __restrict__ rows, int* __restrict__ cnt, int E) {
  int e = blockIdx.x * blockDim.x + threadIdx.x;
  if (e < E) atomicAdd(&cnt[rows[e]], 1);
}

// Exclusive offsets: wave-scan + one global-cursor atomic per wave.
__global__ void offsets_kernel(const int* __restrict__ cnt, int* __restrict__ offs,
                               int* __restrict__ total, int N) {
  int n = blockIdx.x * blockDim.x + threadIdx.x;
  int lane = threadIdx.x & 63;
  int c = (n < N) ? cnt[n] : 0;
  int v = c;
#pragma unroll
  for (int d = 1; d < 64; d <<= 1) {
    int t = __shfl_up(v, d, 64);
    if (lane >= d) v += t;
  }
  int base = 0;
  if (lane == 63) base = atomicAdd(total, v);
  base = __shfl(base, 63, 64);
  if (n < N) offs[n] = base + (v - c);
}

// Scatter edges into per-row buckets; vals fp32 -> bf16 (keeps ws at 45.7 MB).
// offs[] becomes end-pointers afterwards.
__global__ void scatter_kernel(const int* __restrict__ rows, const int* __restrict__ cols,
                               const float* __restrict__ vals, int* __restrict__ offs,
                               int* __restrict__ bcol, u16* __restrict__ bval, int E) {
  int e = blockIdx.x * blockDim.x + threadIdx.x;
  if (e >= E) return;
  int pos = atomicAdd(&offs[rows[e]], 1);
  bcol[pos] = cols[e];
  bval[pos] = (u16)f32_to_bf16_rne(vals[e]);
}

// One wave per node; lane owns dims (2l, 2l+1) = one h dword. Per edge:
// sequential uniform bcol/bval reads + one coalesced 256B h gather. fp32
// register accumulate, ReLU, coalesced float2 store. No float atomics.
__global__ __launch_bounds__(256) void agg_kernel(const int* __restrict__ cnt,
                                                  const int* __restrict__ offs,
                                                  const int* __restrict__ bcol,
                                                  const u16* __restrict__ bval,
                                                  const u32* __restrict__ h,
                                                  float* __restrict__ out, int N) {
  int lane = threadIdx.x & 63;
  int node = blockIdx.x * 4 + (threadIdx.x >> 6);
  if (node >= N) return;
  int end = offs[node];
  int start = end - cnt[node];
  float a0 = 0.f, a1 = 0.f;
  for (int e = start; e < end; ++e) {
    float v = bf16_to_f32(bval[e]);
    u32 d = h[(size_t)bcol[e] * DIM2 + lane];
    a0 += v * __uint_as_float(d << 16);
    a1 += v * __uint_as_float(d & 0xffff0000u);
  }
  float2 o2 = make_float2(fmaxf(a0, 0.f), fmaxf(a1, 0.f));
  *(float2*)(out + (size_t)node * DIM + 2 * lane) = o2;
}

extern "C" void kernel_launch(void* const* d_in, const int* in_sizes, int n_in,
                              void* d_out, int out_size, void* d_ws, size_t ws_size,
                              hipStream_t stream) {
  const float* x    = (const float*)d_in[0];  // fp32 [N,128]
  const int*   rows = (const int*)d_in[1];    // int32 [E]
  const int*   cols = (const int*)d_in[2];    // int32 [E]
  const float* vals = (const float*)d_in[3];  // fp32 [E]
  const float* W    = (const float*)d_in[4];  // fp32 [128,128]

  const int N = in_sizes[0] / DIM;  // 100000
  const int E = in_sizes[1];        // 3200000

  char* wsb = (char*)d_ws;
  u16* h = (u16*)wsb;                                   // 25.6 MB bf16
  size_t o1 = (size_t)N * DIM * sizeof(u16);
  int* cnt   = (int*)(wsb + o1);                        // N*4
  int* offs  = (int*)(wsb + o1 + (size_t)N * 4);        // N*4
  int* total = (int*)(wsb + o1 + (size_t)N * 8);        // 4 (pad 256)
  int* bcol  = (int*)(wsb + o1 + (size_t)N * 8 + 256);  // E*4 = 12.8 MB
  u16* bval  = (u16*)(wsb + o1 + (size_t)N * 8 + 256 + (size_t)E * 4);  // E*2

  zero_kernel<<<(N + 255) / 256, 256, 0, stream>>>(cnt, total, N);
  gemm_f32<<<(N + 1) / 2, 256, 0, stream>>>(x, W, h, N);
  hist_kernel<<<(E + 255) / 256, 256, 0, stream>>>(rows, cnt, E);
  offsets_kernel<<<(N + 255) / 256, 256, 0, stream>>>(cnt, offs, total, N);
  scatter_kernel<<<(E + 255) / 256, 256, 0, stream>>>(rows, cols, vals, offs, bcol, bval, E);
  agg_kernel<<<(N + 3) / 4, 256, 0, stream>>>(cnt, offs, bcol, bval, (const u32*)h,
                                              (float*)d_out, N);
}

// Round 9
// 748.123 us; speedup vs baseline: 2.7031x; 2.7031x over previous
//
#include <hip/hip_runtime.h>
#include <stdint.h>

typedef unsigned short u16;
typedef unsigned int u32;
typedef __attribute__((ext_vector_type(8))) short short8;
typedef __attribute__((ext_vector_type(4))) float floatx4;

#define DIM 128
#define DIM2 64  // h dwords per row (2 bf16 per dword)

__device__ __forceinline__ u32 f32_to_bf16_rne(float f) {
  u32 u = __float_as_uint(f);
  u32 r = u + 0x7fffu + ((u >> 16) & 1u);
  return r >> 16;
}
__device__ __forceinline__ float bf16_to_f32(u32 u) { return __uint_as_float(u << 16); }
__device__ __forceinline__ u32 pack2bf16(float a, float b) {
  return f32_to_bf16_rne(a) | (f32_to_bf16_rne(b) << 16);
}

union FragU {
  u32 d[4];
  short8 s;
};

// h = x @ W^T via bf16 MFMA (fp32 inputs converted in-kernel; h out bf16).
// Block = 256 threads = 4 waves = 64 nodes. W staged fp32->bf16 into 32KB LDS
// once per block, swizzled in 16B k-groups: group g of row o lands at slot
// (g+o)&15 -> B-frag ds_read_b128 is bank-conflict-free (2-way = free).
// Wave = 16 nodes x 128 outs = 8 o-tiles x 4 k-steps of mfma_f32_16x16x32_bf16.
// Frag maps (verified m89/m120): A[m=lane&15][k=(lane>>4)*8+j]; B same with
// n=lane&15; D col=lane&15, row=(lane>>4)*4+reg.
__global__ __launch_bounds__(256) void gemm_mfma(const float* __restrict__ x,
                                                 const float* __restrict__ W,
                                                 u16* __restrict__ h, int N) {
  __shared__ u32 Wl[DIM * DIM2];  // 32 KB: row o = 64 dwords, 16 slots x 4
  int tid = threadIdx.x;
  // stage W: 2048 groups of 8 elements; 8 groups per thread, coalesced reads
#pragma unroll
  for (int i = 0; i < 8; ++i) {
    int ga = tid + 256 * i;
    int o = ga >> 4, g = ga & 15;
    const float* src = W + (size_t)o * DIM + g * 8;
    floatx4 f0 = *(const floatx4*)src;
    floatx4 f1 = *(const floatx4*)(src + 4);
    int slot = (g + o) & 15;
    u32* dst = &Wl[o * DIM2 + slot * 4];
    dst[0] = pack2bf16(f0.x, f0.y);
    dst[1] = pack2bf16(f0.z, f0.w);
    dst[2] = pack2bf16(f1.x, f1.y);
    dst[3] = pack2bf16(f1.z, f1.w);
  }
  __syncthreads();

  int lane = tid & 63;
  int wave = tid >> 6;
  int nodeBase = (blockIdx.x * 4 + wave) * 16;
  if (nodeBase >= N) return;
  int m = lane & 15;
  int kg = lane >> 4;

  // A fragments: convert 8 fp32 of x per k-step
  short8 a[4];
  const float* xr = x + (size_t)(nodeBase + m) * DIM + kg * 8;
#pragma unroll
  for (int kt = 0; kt < 4; ++kt) {
    floatx4 f0 = *(const floatx4*)(xr + kt * 32);
    floatx4 f1 = *(const floatx4*)(xr + kt * 32 + 4);
    FragU fu;
    fu.d[0] = pack2bf16(f0.x, f0.y);
    fu.d[1] = pack2bf16(f0.z, f0.w);
    fu.d[2] = pack2bf16(f1.x, f1.y);
    fu.d[3] = pack2bf16(f1.z, f1.w);
    a[kt] = fu.s;
  }

#pragma unroll
  for (int ot = 0; ot < 8; ++ot) {
    int o = ot * 16 + m;
    floatx4 acc = {0.f, 0.f, 0.f, 0.f};
#pragma unroll
    for (int kt = 0; kt < 4; ++kt) {
      int slot = (kt * 4 + kg + o) & 15;
      short8 b = *(short8*)&Wl[o * DIM2 + slot * 4];
      acc = __builtin_amdgcn_mfma_f32_16x16x32_bf16(a[kt], b, acc, 0, 0, 0);
    }
#pragma unroll
    for (int r = 0; r < 4; ++r) {
      int node = nodeBase + kg * 4 + r;
      h[(size_t)node * DIM + ot * 16 + m] = (u16)f32_to_bf16_rne(acc[r]);
    }
  }
}

__global__ void zero_kernel(int* __restrict__ cnt, int* __restrict__ total, int N) {
  int i = blockIdx.x * blockDim.x + threadIdx.x;
  if (i < N) cnt[i] = 0;
  if (i == 0) *total = 0;
}

__global__ void hist_kernel(const int* __restrict__ rows, int* __restrict__ cnt, int E) {
  int e = blockIdx.x * blockDim.x + threadIdx.x;
  if (e < E) atomicAdd(&cnt[rows[e]], 1);
}

// Exclusive offsets: wave-scan + one global-cursor atomic per wave.
__global__ void offsets_kernel(const int* __restrict__ cnt, int* __restrict__ offs,
                               int* __restrict__ total, int N) {
  int n = blockIdx.x * blockDim.x + threadIdx.x;
  int lane = threadIdx.x & 63;
  int c = (n < N) ? cnt[n] : 0;
  int v = c;
#pragma unroll
  for (int d = 1; d < 64; d <<= 1) {
    int t = __shfl_up(v, d, 64);
    if (lane >= d) v += t;
  }
  int base = 0;
  if (lane == 63) base = atomicAdd(total, v);
  base = __shfl(base, 63, 64);
  if (n < N) offs[n] = base + (v - c);
}

// Scatter edges into per-row buckets; vals fp32 -> bf16. offs[] -> end ptrs.
__global__ void scatter_kernel(const int* __restrict__ rows, const int* __restrict__ cols,
                               const float* __restrict__ vals, int* __restrict__ offs,
                               int* __restrict__ bcol, u16* __restrict__ bval, int E) {
  int e = blockIdx.x * blockDim.x + threadIdx.x;
  if (e >= E) return;
  int pos = atomicAdd(&offs[rows[e]], 1);
  bcol[pos] = cols[e];
  bval[pos] = (u16)f32_to_bf16_rne(vals[e]);
}

// One wave per node; lane owns dims (2l, 2l+1) = one h dword. fp32 register
// accumulate, ReLU, coalesced float2 store. No float atomics anywhere.
__global__ __launch_bounds__(256) void agg_kernel(const int* __restrict__ cnt,
                                                  const int* __restrict__ offs,
                                                  const int* __restrict__ bcol,
                                                  const u16* __restrict__ bval,
                                                  const u32* __restrict__ h,
                                                  float* __restrict__ out, int N) {
  int lane = threadIdx.x & 63;
  int node = blockIdx.x * 4 + (threadIdx.x >> 6);
  if (node >= N) return;
  int end = offs[node];
  int start = end - cnt[node];
  float a0 = 0.f, a1 = 0.f;
  for (int e = start; e < end; ++e) {
    float v = bf16_to_f32(bval[e]);
    u32 d = h[(size_t)bcol[e] * DIM2 + lane];
    a0 += v * __uint_as_float(d << 16);
    a1 += v * __uint_as_float(d & 0xffff0000u);
  }
  float2 o2 = make_float2(fmaxf(a0, 0.f), fmaxf(a1, 0.f));
  *(float2*)(out + (size_t)node * DIM + 2 * lane) = o2;
}

extern "C" void kernel_launch(void* const* d_in, const int* in_sizes, int n_in,
                              void* d_out, int out_size, void* d_ws, size_t ws_size,
                              hipStream_t stream) {
  const float* x    = (const float*)d_in[0];  // fp32 [N,128]
  const int*   rows = (const int*)d_in[1];    // int32 [E]
  const int*   cols = (const int*)d_in[2];    // int32 [E]
  const float* vals = (const float*)d_in[3];  // fp32 [E]
  const float* W    = (const float*)d_in[4];  // fp32 [128,128]

  const int N = in_sizes[0] / DIM;  // 100000
  const int E = in_sizes[1];        // 3200000

  char* wsb = (char*)d_ws;
  u16* h = (u16*)wsb;                                   // 25.6 MB bf16
  size_t o1 = (size_t)N * DIM * sizeof(u16);
  int* cnt   = (int*)(wsb + o1);                        // N*4
  int* offs  = (int*)(wsb + o1 + (size_t)N * 4);        // N*4
  int* total = (int*)(wsb + o1 + (size_t)N * 8);        // 4 (pad 256)
  int* bcol  = (int*)(wsb + o1 + (size_t)N * 8 + 256);  // E*4 = 12.8 MB
  u16* bval  = (u16*)(wsb + o1 + (size_t)N * 8 + 256 + (size_t)E * 4);  // E*2

  zero_kernel<<<(N + 255) / 256, 256, 0, stream>>>(cnt, total, N);
  gemm_mfma<<<(N + 63) / 64, 256, 0, stream>>>(x, W, h, N);
  hist_kernel<<<(E + 255) / 256, 256, 0, stream>>>(rows, cnt, E);
  offsets_kernel<<<(N + 255) / 256, 256, 0, stream>>>(cnt, offs, total, N);
  scatter_kernel<<<(E + 255) / 256, 256, 0, stream>>>(rows, cols, vals, offs, bcol, bval, E);
  agg_kernel<<<(N + 3) / 4, 256, 0, stream>>>(cnt, offs, bcol, bval, (const u32*)h,
                                              (float*)d_out, N);
}

// Round 10
// 594.700 us; speedup vs baseline: 3.4004x; 1.2580x over previous
//
#include <hip/hip_runtime.h>
#include <stdint.h>

typedef unsigned short u16;
typedef unsigned int u32;
typedef __attribute__((ext_vector_type(8))) short short8;
typedef __attribute__((ext_vector_type(4))) float floatx4;

#define DIM 128
#define DIM2 64  // h dwords per row (2 bf16 per dword)

__device__ __forceinline__ u32 f32_to_bf16_rne(float f) {
  u32 u = __float_as_uint(f);
  u32 r = u + 0x7fffu + ((u >> 16) & 1u);
  return r >> 16;
}
__device__ __forceinline__ float bf16_to_f32(u32 u) { return __uint_as_float(u << 16); }
__device__ __forceinline__ u32 pack2bf16(float a, float b) {
  return f32_to_bf16_rne(a) | (f32_to_bf16_rne(b) << 16);
}

union FragU {
  u32 d[4];
  short8 s;
};

// h = x @ W^T via bf16 MFMA (fp32 inputs converted in-kernel; h out bf16).
// See R8 comments; verified frag maps m89/m120.
__global__ __launch_bounds__(256) void gemm_mfma(const float* __restrict__ x,
                                                 const float* __restrict__ W,
                                                 u16* __restrict__ h, int N) {
  __shared__ u32 Wl[DIM * DIM2];  // 32 KB
  int tid = threadIdx.x;
#pragma unroll
  for (int i = 0; i < 8; ++i) {
    int ga = tid + 256 * i;
    int o = ga >> 4, g = ga & 15;
    const float* src = W + (size_t)o * DIM + g * 8;
    floatx4 f0 = *(const floatx4*)src;
    floatx4 f1 = *(const floatx4*)(src + 4);
    int slot = (g + o) & 15;
    u32* dst = &Wl[o * DIM2 + slot * 4];
    dst[0] = pack2bf16(f0.x, f0.y);
    dst[1] = pack2bf16(f0.z, f0.w);
    dst[2] = pack2bf16(f1.x, f1.y);
    dst[3] = pack2bf16(f1.z, f1.w);
  }
  __syncthreads();

  int lane = tid & 63;
  int wave = tid >> 6;
  int nodeBase = (blockIdx.x * 4 + wave) * 16;
  if (nodeBase >= N) return;
  int m = lane & 15;
  int kg = lane >> 4;

  short8 a[4];
  const float* xr = x + (size_t)(nodeBase + m) * DIM + kg * 8;
#pragma unroll
  for (int kt = 0; kt < 4; ++kt) {
    floatx4 f0 = *(const floatx4*)(xr + kt * 32);
    floatx4 f1 = *(const floatx4*)(xr + kt * 32 + 4);
    FragU fu;
    fu.d[0] = pack2bf16(f0.x, f0.y);
    fu.d[1] = pack2bf16(f0.z, f0.w);
    fu.d[2] = pack2bf16(f1.x, f1.y);
    fu.d[3] = pack2bf16(f1.z, f1.w);
    a[kt] = fu.s;
  }

#pragma unroll
  for (int ot = 0; ot < 8; ++ot) {
    int o = ot * 16 + m;
    floatx4 acc = {0.f, 0.f, 0.f, 0.f};
#pragma unroll
    for (int kt = 0; kt < 4; ++kt) {
      int slot = (kt * 4 + kg + o) & 15;
      short8 b = *(short8*)&Wl[o * DIM2 + slot * 4];
      acc = __builtin_amdgcn_mfma_f32_16x16x32_bf16(a[kt], b, acc, 0, 0, 0);
    }
#pragma unroll
    for (int r = 0; r < 4; ++r) {
      int node = nodeBase + kg * 4 + r;
      h[(size_t)node * DIM + ot * 16 + m] = (u16)f32_to_bf16_rne(acc[r]);
    }
  }
}

__global__ void zero_kernel(int* __restrict__ cnt, int* __restrict__ total, int N) {
  int i = blockIdx.x * blockDim.x + threadIdx.x;
  if (i < N) cnt[i] = 0;
  if (i == 0) *total = 0;
}

__global__ void hist_kernel(const int* __restrict__ rows, int* __restrict__ cnt, int E) {
  int e = blockIdx.x * blockDim.x + threadIdx.x;
  if (e < E) atomicAdd(&cnt[rows[e]], 1);
}

__global__ void offsets_kernel(const int* __restrict__ cnt, int* __restrict__ offs,
                               int* __restrict__ total, int N) {
  int n = blockIdx.x * blockDim.x + threadIdx.x;
  int lane = threadIdx.x & 63;
  int c = (n < N) ? cnt[n] : 0;
  int v = c;
#pragma unroll
  for (int d = 1; d < 64; d <<= 1) {
    int t = __shfl_up(v, d, 64);
    if (lane >= d) v += t;
  }
  int base = 0;
  if (lane == 63) base = atomicAdd(total, v);
  base = __shfl(base, 63, 64);
  if (n < N) offs[n] = base + (v - c);
}

__global__ void scatter_kernel(const int* __restrict__ rows, const int* __restrict__ cols,
                               const float* __restrict__ vals, int* __restrict__ offs,
                               int* __restrict__ bcol, u16* __restrict__ bval, int E) {
  int e = blockIdx.x * blockDim.x + threadIdx.x;
  if (e >= E) return;
  int pos = atomicAdd(&offs[rows[e]], 1);
  bcol[pos] = cols[e];
  bval[pos] = (u16)f32_to_bf16_rne(vals[e]);
}

// One wave per node; lane owns dims (2l, 2l+1) = one h dword. Edge loop
// unrolled 4x: four independent h-row gathers in flight per wave (R9 showed
// latency-bound at ~1 outstanding: 218 cyc/edge/SIMD, VGPR=12 -> headroom).
__global__ __launch_bounds__(256) void agg_kernel(const int* __restrict__ cnt,
                                                  const int* __restrict__ offs,
                                                  const int* __restrict__ bcol,
                                                  const u16* __restrict__ bval,
                                                  const u32* __restrict__ h,
                                                  float* __restrict__ out, int N) {
  int lane = threadIdx.x & 63;
  int node = blockIdx.x * 4 + (threadIdx.x >> 6);
  if (node >= N) return;
  int end = offs[node];
  int start = end - cnt[node];
  float a0 = 0.f, a1 = 0.f;
  int e = start;
  for (; e + 4 <= end; e += 4) {
    int c0 = bcol[e], c1 = bcol[e + 1], c2 = bcol[e + 2], c3 = bcol[e + 3];
    float v0 = bf16_to_f32(bval[e]);
    float v1 = bf16_to_f32(bval[e + 1]);
    float v2 = bf16_to_f32(bval[e + 2]);
    float v3 = bf16_to_f32(bval[e + 3]);
    u32 d0 = h[(size_t)c0 * DIM2 + lane];
    u32 d1 = h[(size_t)c1 * DIM2 + lane];
    u32 d2 = h[(size_t)c2 * DIM2 + lane];
    u32 d3 = h[(size_t)c3 * DIM2 + lane];
    a0 += v0 * bf16_to_f32(d0 & 0xffffu);
    a1 += v0 * bf16_to_f32(d0 >> 16);
    a0 += v1 * bf16_to_f32(d1 & 0xffffu);
    a1 += v1 * bf16_to_f32(d1 >> 16);
    a0 += v2 * bf16_to_f32(d2 & 0xffffu);
    a1 += v2 * bf16_to_f32(d2 >> 16);
    a0 += v3 * bf16_to_f32(d3 & 0xffffu);
    a1 += v3 * bf16_to_f32(d3 >> 16);
  }
  for (; e < end; ++e) {
    float v = bf16_to_f32(bval[e]);
    u32 d = h[(size_t)bcol[e] * DIM2 + lane];
    a0 += v * bf16_to_f32(d & 0xffffu);
    a1 += v * bf16_to_f32(d >> 16);
  }
  float2 o2 = make_float2(fmaxf(a0, 0.f), fmaxf(a1, 0.f));
  *(float2*)(out + (size_t)node * DIM + 2 * lane) = o2;
}

extern "C" void kernel_launch(void* const* d_in, const int* in_sizes, int n_in,
                              void* d_out, int out_size, void* d_ws, size_t ws_size,
                              hipStream_t stream) {
  const float* x    = (const float*)d_in[0];  // fp32 [N,128]
  const int*   rows = (const int*)d_in[1];    // int32 [E]
  const int*   cols = (const int*)d_in[2];    // int32 [E]
  const float* vals = (const float*)d_in[3];  // fp32 [E]
  const float* W    = (const float*)d_in[4];  // fp32 [128,128]

  const int N = in_sizes[0] / DIM;  // 100000
  const int E = in_sizes[1];        // 3200000

  char* wsb = (char*)d_ws;
  u16* h = (u16*)wsb;                                   // 25.6 MB bf16
  size_t o1 = (size_t)N * DIM * sizeof(u16);
  int* cnt   = (int*)(wsb + o1);                        // N*4
  int* offs  = (int*)(wsb + o1 + (size_t)N * 4);        // N*4
  int* total = (int*)(wsb + o1 + (size_t)N * 8);        // 4 (pad 256)
  int* bcol  = (int*)(wsb + o1 + (size_t)N * 8 + 256);  // E*4 = 12.8 MB
  u16* bval  = (u16*)(wsb + o1 + (size_t)N * 8 + 256 + (size_t)E * 4);  // E*2

  zero_kernel<<<(N + 255) / 256, 256, 0, stream>>>(cnt, total, N);
  gemm_mfma<<<(N + 63) / 64, 256, 0, stream>>>(x, W, h, N);
  hist_kernel<<<(E + 255) / 256, 256, 0, stream>>>(rows, cnt, E);
  offsets_kernel<<<(N + 255) / 256, 256, 0, stream>>>(cnt, offs, total, N);
  scatter_kernel<<<(E + 255) / 256, 256, 0, stream>>>(rows, cols, vals, offs, bcol, bval, E);
  agg_kernel<<<(N + 3) / 4, 256, 0, stream>>>(cnt, offs, bcol, bval, (const u32*)h,
                                              (float*)d_out, N);
}